// Round 2
// baseline (108.153 us; speedup 1.0000x reference)
//
#include <hip/hip_runtime.h>
#include <hip/hip_bf16.h>
#include <cstdint>
#include <cstddef>

typedef _Float16 f16x8 __attribute__((ext_vector_type(8)));
typedef _Float16 f16x4 __attribute__((ext_vector_type(4)));
typedef float    f32x4 __attribute__((ext_vector_type(4)));

#define MFMA16(a,b,c) __builtin_amdgcn_mfma_f32_16x16x32_f16((a),(b),(c),0,0,0)

// Workspace layout (in _Float16 elements):
//   W1T  [15][64][256] at 0        (245760)
//   W16T [64][384]     at 245760   (24576)   k-index sp: x col = 1816+sp, zero for sp<4 or sp>=360
//   W2T  [4][64][256]  at 270336   (65536)
//   W3T  [272][256]    at 335872   (69632)   rows >= 260 are zero
// total 405504 halfs = 811008 bytes

__global__ void tea_prep(const float* __restrict__ W1, const float* __restrict__ W16,
                         const float* __restrict__ W2, const float* __restrict__ W3,
                         _Float16* __restrict__ ws)
{
    int i = blockIdx.x * blockDim.x + threadIdx.x;
    if (i < 245760) {
        int k = i >> 14, r = i & 16383, o = r >> 8, s = r & 255;
        ws[i] = (_Float16)W1[((k << 8) | s) * 64 + o];
    } else if (i < 270336) {
        int r = i - 245760, o = r / 384, sp = r - o * 384;
        float v = (sp >= 4 && sp < 360) ? W16[(sp - 4) * 64 + o] : 0.f;
        ws[i] = (_Float16)v;
    } else if (i < 335872) {
        int r = i - 270336, g = r >> 14, rr = r & 16383, o = rr >> 8, s = rr & 255;
        ws[i] = (_Float16)W2[((g << 8) | s) * 64 + o];
    } else if (i < 405504) {
        int r = i - 335872, o = r >> 8, s = r & 255;
        ws[i] = (_Float16)((o < 260) ? W3[s * 260 + o] : 0.f);
    }
}

// One 16x64-output GEMM pass over K = NKK*32.  4 waves; wave w owns the 16x16
// tile at cols w*16.  A and B fragments use the SAME (lanegroup,elem)->k map
// (kk*32+8*lg+j) so any HW K-permutation cancels.  C/D: col=lane&15,
// row=4*(lane>>4)+reg.
// ACH: A from the 3-slot x-chunk ring (xbase = global x column base);
// else A from a [16][264] LDS matrix.  B always straight from global (L2).
template<bool ACH, int NKK>
__device__ __forceinline__ void gemm16(
    int w, int lg, int lr,
    const _Float16* __restrict__ xch, int xbase,
    const _Float16* __restrict__ amat,
    const _Float16* __restrict__ bglob, int bstride,
    const float* __restrict__ bias,
    _Float16* __restrict__ dst, int dbase)
{
    f32x4 acc = {0.f, 0.f, 0.f, 0.f};
    const _Float16* brow = bglob + (size_t)(w * 16 + lr) * bstride + lg * 8;
    #pragma unroll
    for (int kk = 0; kk < NKK; ++kk) {
        int kloc = kk * 32 + lg * 8;
        f16x8 A, B;
        if (ACH) {
            int cg = xbase + kloc;
            int slot = (cg >> 7) % 3;
            A = *(const f16x8*)(xch + (slot * 16 + lr) * 136 + (cg & 127));
        } else {
            A = *(const f16x8*)(amat + lr * 264 + kloc);
        }
        B = *(const f16x8*)(brow + kk * 32);
        acc = MFMA16(A, B, acc);
    }
    float bv = bias[w * 16 + lr];
    #pragma unroll
    for (int j = 0; j < 4; ++j) {
        float v = acc[j] + bv;
        v = v > 0.f ? v : 0.f;
        dst[(lg * 4 + j) * 264 + dbase + w * 16 + lr] = (_Float16)v;
    }
}

// LDS (29952 B -> up to 5 blocks/CU; grid gives 4):
//   xch [3][16][136] f16 at 0      (13056 B)  3-slot ring of 128-col x chunks
//   ysm [16][264]    f16 at 6528   ( 8448 B)  current group's y (4 windows x 64)
//   zsm [16][264]    f16 at 10752  ( 8448 B)  z (layer2 out, 256 cols)
//   phase B: hsm [16][280] f32 at 0 (17920 B) layer3 h, aliases xch+ysm
__global__ __launch_bounds__(256, 4)
void tea_main(const float* __restrict__ x,
              const float* __restrict__ b1,
              const float* __restrict__ b16,
              const float* __restrict__ b2,
              const float* __restrict__ b3,
              const _Float16* __restrict__ ws,
              float* __restrict__ out)
{
    __shared__ _Float16 lds[14976];
    _Float16* xch = lds;              // [3][16][136]
    _Float16* ysm = lds + 6528;       // [16][264]
    _Float16* zsm = lds + 10752;      // [16][264]
    float*    hsm = (float*)lds;      // [16][280] (phase B only)

    const int tid = threadIdx.x;
    const int bid = blockIdx.x;
    const int w  = tid >> 6;
    const int l  = tid & 63;
    const int lg = l >> 4;
    const int lr = l & 15;

    const _Float16* wsW1  = ws;
    const _Float16* wsW16 = ws + 245760;
    const _Float16* wsW2  = ws + 270336;
    const _Float16* wsW3  = ws + 335872;

    const float* xrow = x + (size_t)bid * 16 * 2176;

    float4 creg[2];
    const int crow = tid >> 5;            // 0..7, +8 for creg[1]
    const int ccol = (tid & 31) * 4;

    auto issue_chunk = [&](int c) {
        const float* base = xrow + c * 128;
        creg[0] = *(const float4*)(base + (size_t)crow * 2176 + ccol);
        creg[1] = *(const float4*)(base + (size_t)(crow + 8) * 2176 + ccol);
    };
    auto write_chunk = [&](int c) {
        int slot = c % 3;
        #pragma unroll
        for (int i = 0; i < 2; ++i) {
            f16x4 h;
            h[0] = (_Float16)creg[i].x; h[1] = (_Float16)creg[i].y;
            h[2] = (_Float16)creg[i].z; h[3] = (_Float16)creg[i].w;
            *(f16x4*)(xch + (slot * 16 + crow + i * 8) * 136 + ccol) = h;
        }
    };

    // prologue: chunk 0 staged, chunk 1 in flight
    issue_chunk(0);
    write_chunk(0);
    issue_chunk(1);

    for (int g = 0; g < 4; ++g) {
        #pragma unroll 1
        for (int j = 0; j < 4; ++j) {
            int k = g * 4 + j;                 // k==15 -> y16 pseudo-window
            __syncthreads();                   // prior compute done; chunk k+1 loads consumed
            write_chunk(k + 1);
            __syncthreads();
            if (k + 2 <= 16) issue_chunk(k + 2);   // stays in flight across this pass
            if (k < 15) {
                gemm16<true, 8>(w, lg, lr, xch, 128 * k, nullptr,
                                wsW1 + k * 16384, 256, b1 + k * 64, ysm, (k & 3) * 64);
            } else {
                // y16: x cols 1816+sp; sp>=360 region multiplies zeroed W16T rows
                gemm16<true, 12>(w, lg, lr, xch, 1816, nullptr,
                                 wsW16, 384, b16, ysm, 192);
            }
        }
        // layer 2, group g
        __syncthreads();
        gemm16<false, 8>(w, lg, lr, nullptr, 0, ysm,
                         wsW2 + g * 16384, 256, b2 + g * 64, zsm, g * 64);
    }

    // layer 3: wave w does col-tiles t = w, w+4, ...; B straight from L2
    __syncthreads();
    {
        f16x8 az[8];
        #pragma unroll
        for (int kk = 0; kk < 8; ++kk)
            az[kk] = *(const f16x8*)(zsm + lr * 264 + kk * 32 + lg * 8);
        #pragma unroll 1
        for (int t = w; t < 17; t += 4) {
            f32x4 acc = {0.f, 0.f, 0.f, 0.f};
            #pragma unroll
            for (int kk = 0; kk < 8; ++kk) {
                f16x8 B = *(const f16x8*)(wsW3 + (size_t)(t * 16 + lr) * 256 + kk * 32 + lg * 8);
                acc = MFMA16(az[kk], B, acc);
            }
            int o = t * 16 + lr;
            float bv = (o < 260) ? b3[o] : 0.f;
            #pragma unroll
            for (int jj = 0; jj < 4; ++jj) {
                float v = acc[jj] + bv; v = v > 0.f ? v : 0.f;
                hsm[(lg * 4 + jj) * 280 + o] = v;
            }
        }
    }
    __syncthreads();

    // pooling (10 classes x 26) + softmax; threads 0..15 each own one row
    if (tid < 16) {
        int row = tid;
        float p[10];
        #pragma unroll
        for (int c = 0; c < 10; ++c) {
            float s = 0.f;
            #pragma unroll
            for (int u = 0; u < 26; ++u) s += hsm[row * 280 + c * 26 + u];
            p[c] = s;
        }
        float m = p[0];
        #pragma unroll
        for (int c = 1; c < 10; ++c) m = fmaxf(m, p[c]);
        float e[10], se = 0.f;
        #pragma unroll
        for (int c = 0; c < 10; ++c) { e[c] = expf(p[c] - m); se += e[c]; }
        float inv = 1.f / se;
        float* orow = out + (size_t)(bid * 16 + row) * 10;
        #pragma unroll
        for (int c = 0; c < 10; ++c) orow[c] = e[c] * inv;
    }
}

extern "C" void kernel_launch(void* const* d_in, const int* in_sizes, int n_in,
                              void* d_out, int out_size, void* d_ws, size_t ws_size,
                              hipStream_t stream)
{
    const float* x   = (const float*)d_in[0];
    const float* W1  = (const float*)d_in[1];
    const float* b1  = (const float*)d_in[2];
    const float* W16 = (const float*)d_in[3];
    const float* b16 = (const float*)d_in[4];
    const float* W2  = (const float*)d_in[5];
    const float* b2  = (const float*)d_in[6];
    const float* W3  = (const float*)d_in[7];
    const float* b3  = (const float*)d_in[8];
    float*    out = (float*)d_out;
    _Float16* ws  = (_Float16*)d_ws;

    tea_prep<<<1584, 256, 0, stream>>>(W1, W16, W2, W3, ws);
    tea_main<<<1024, 256, 0, stream>>>(x, b1, b16, b2, b3, ws, out);
}

// Round 3
// 70.481 us; speedup vs baseline: 1.5345x; 1.5345x over previous
//
#include <hip/hip_runtime.h>
#include <hip/hip_bf16.h>
#include <cstdint>
#include <cstddef>

typedef _Float16 f16x8 __attribute__((ext_vector_type(8)));
typedef _Float16 f16x4 __attribute__((ext_vector_type(4)));
typedef float    f32x4 __attribute__((ext_vector_type(4)));

#define MFMA16(a,b,c) __builtin_amdgcn_mfma_f32_16x16x32_f16((a),(b),(c),0,0,0)

// Workspace layout (in _Float16 elements):
//   W1T  [15][64][256] at 0        (245760)
//   W16T [64][384]     at 245760   (24576)   k-index sp: x col = 1816+sp, zero for sp<4 or sp>=360
//   W2T  [4][64][256]  at 270336   (65536)
//   W3T  [272][256]    at 335872   (69632)   rows >= 260 are zero
__global__ void tea_prep(const float* __restrict__ W1, const float* __restrict__ W16,
                         const float* __restrict__ W2, const float* __restrict__ W3,
                         _Float16* __restrict__ ws)
{
    int i = blockIdx.x * blockDim.x + threadIdx.x;
    if (i < 245760) {
        int k = i >> 14, r = i & 16383, o = r >> 8, s = r & 255;
        ws[i] = (_Float16)W1[((k << 8) | s) * 64 + o];
    } else if (i < 270336) {
        int r = i - 245760, o = r / 384, sp = r - o * 384;
        float v = (sp >= 4 && sp < 360) ? W16[(sp - 4) * 64 + o] : 0.f;
        ws[i] = (_Float16)v;
    } else if (i < 335872) {
        int r = i - 270336, g = r >> 14, rr = r & 16383, o = rr >> 8, s = rr & 255;
        ws[i] = (_Float16)W2[((g << 8) | s) * 64 + o];
    } else if (i < 405504) {
        int r = i - 335872, o = r >> 8, s = r & 255;
        ws[i] = (_Float16)((o < 260) ? W3[s * 260 + o] : 0.f);
    }
}

// LDS (68608 B -> 2 blocks/CU):
//   xch [4][32][136] f16 at 0      (34816 B)  4-slot ring of 128-col x chunks
//   ysm [32][264]    f16 at 17408h ( 16896 B)
//   zsm [32][264]    f16 at 25856h ( 16896 B)
//   phase B: hsm [32][280] f32 at byte 0 (35840 B, aliases ring+ysm head; zsm safe)
__global__ __launch_bounds__(256, 2)
void tea_main(const float* __restrict__ x,
              const float* __restrict__ b1,
              const float* __restrict__ b16,
              const float* __restrict__ b2,
              const float* __restrict__ b3,
              const _Float16* __restrict__ ws,
              float* __restrict__ out)
{
    __shared__ _Float16 lds[34304];
    _Float16* xch = lds;               // [4][32][136]
    _Float16* ysm = lds + 17408;       // [32][264]
    _Float16* zsm = lds + 25856;       // [32][264]
    float*    hsm = (float*)lds;       // [32][280] (phase B only)

    const int tid = threadIdx.x;
    const int bid = blockIdx.x;
    const int w  = tid >> 6;
    const int l  = tid & 63;
    const int lg = l >> 4;
    const int lr = l & 15;

    const _Float16* wsW1  = ws;
    const _Float16* wsW16 = ws + 245760;
    const _Float16* wsW2  = ws + 270336;
    const _Float16* wsW3  = ws + 335872;

    const float* xrow = x + (size_t)bid * 32 * 2176;

    const int cr_row = tid >> 3;          // 0..31
    const int cr_col = (tid & 7) * 16;    // 0,16,..,112

    float4 creg[4][4];                    // [chunk&3][4 x float4] = 16 cols
    f16x8  Ba[8], Bb[8];
    f32x4  acc0, acc1;

#define PH_TOP() do { \
    asm volatile("s_waitcnt lgkmcnt(0)" ::: "memory"); \
    __builtin_amdgcn_s_barrier(); \
    __builtin_amdgcn_sched_barrier(0); } while (0)

#define ISSUE(C) do { \
    const float* _p = xrow + (size_t)cr_row * 2176 + (C) * 128 + cr_col; \
    creg[(C) & 3][0] = *(const float4*)(_p); \
    creg[(C) & 3][1] = *(const float4*)(_p + 4); \
    creg[(C) & 3][2] = *(const float4*)(_p + 8); \
    creg[(C) & 3][3] = *(const float4*)(_p + 12); } while (0)

#define WRITECH(C) do { \
    _Float16* _d = xch + (((C) & 3) * 32 + cr_row) * 136 + cr_col; \
    f16x8 _h; float4 _a, _b4; \
    _a = creg[(C) & 3][0]; _b4 = creg[(C) & 3][1]; \
    _h[0]=(_Float16)_a.x; _h[1]=(_Float16)_a.y; _h[2]=(_Float16)_a.z; _h[3]=(_Float16)_a.w; \
    _h[4]=(_Float16)_b4.x; _h[5]=(_Float16)_b4.y; _h[6]=(_Float16)_b4.z; _h[7]=(_Float16)_b4.w; \
    *(f16x8*)_d = _h; \
    _a = creg[(C) & 3][2]; _b4 = creg[(C) & 3][3]; \
    _h[0]=(_Float16)_a.x; _h[1]=(_Float16)_a.y; _h[2]=(_Float16)_a.z; _h[3]=(_Float16)_a.w; \
    _h[4]=(_Float16)_b4.x; _h[5]=(_Float16)_b4.y; _h[6]=(_Float16)_b4.z; _h[7]=(_Float16)_b4.w; \
    *(f16x8*)(_d + 8) = _h; } while (0)

#define LOADB8(DST, PTR, STR) do { \
    const _Float16* _q = (PTR) + (size_t)(w * 16 + lr) * (STR) + lg * 8; \
    _Pragma("unroll") \
    for (int _i = 0; _i < 8; ++_i) DST[_i] = *(const f16x8*)(_q + _i * 32); } while (0)

#define LOADB4(DST, PTR, STR, K0) do { \
    const _Float16* _q = (PTR) + (size_t)(w * 16 + lr) * (STR) + lg * 8; \
    _Pragma("unroll") \
    for (int _i = 0; _i < 4; ++_i) DST[_i] = *(const f16x8*)(_q + ((K0) + _i) * 32); } while (0)

    // window-pass compute: A from ring (xbase = global x col base), B from BUSE regs
#define WCOMP(XBASE, NKK0, NKK, BUSE, INIT, STOREY, BIAS, DBASE) do { \
    if (INIT) { acc0 = (f32x4){0.f,0.f,0.f,0.f}; acc1 = acc0; } \
    _Pragma("unroll") \
    for (int _kk = 0; _kk < (NKK); ++_kk) { \
        int _cg = (XBASE) + ((NKK0) + _kk) * 32 + lg * 8; \
        int _sl = (_cg >> 7) & 3, _off = _cg & 127; \
        const _Float16* _pa = xch + (_sl * 32 + lr) * 136 + _off; \
        f16x8 _A0 = *(const f16x8*)_pa; \
        f16x8 _A1 = *(const f16x8*)(_pa + 16 * 136); \
        acc0 = MFMA16(_A0, BUSE[_kk], acc0); \
        acc1 = MFMA16(_A1, BUSE[_kk], acc1); \
    } \
    if (STOREY) { \
        float _bv = (BIAS)[w * 16 + lr]; \
        _Pragma("unroll") \
        for (int _j = 0; _j < 4; ++_j) { \
            float _v0 = acc0[_j] + _bv; _v0 = _v0 > 0.f ? _v0 : 0.f; \
            ysm[(lg * 4 + _j) * 264 + (DBASE) + w * 16 + lr] = (_Float16)_v0; \
            float _v1 = acc1[_j] + _bv; _v1 = _v1 > 0.f ? _v1 : 0.f; \
            ysm[(16 + lg * 4 + _j) * 264 + (DBASE) + w * 16 + lr] = (_Float16)_v1; \
        } \
    } } while (0)

#define L2COMP(BUSE, G) do { \
    acc0 = (f32x4){0.f,0.f,0.f,0.f}; acc1 = acc0; \
    _Pragma("unroll") \
    for (int _kk = 0; _kk < 8; ++_kk) { \
        int _kl = _kk * 32 + lg * 8; \
        const _Float16* _pa = ysm + lr * 264 + _kl; \
        f16x8 _A0 = *(const f16x8*)_pa; \
        f16x8 _A1 = *(const f16x8*)(_pa + 16 * 264); \
        acc0 = MFMA16(_A0, BUSE[_kk], acc0); \
        acc1 = MFMA16(_A1, BUSE[_kk], acc1); \
    } \
    { float _bv = b2[(G) * 64 + w * 16 + lr]; \
      _Pragma("unroll") \
      for (int _j = 0; _j < 4; ++_j) { \
        float _v0 = acc0[_j] + _bv; _v0 = _v0 > 0.f ? _v0 : 0.f; \
        zsm[(lg * 4 + _j) * 264 + (G) * 64 + w * 16 + lr] = (_Float16)_v0; \
        float _v1 = acc1[_j] + _bv; _v1 = _v1 > 0.f ? _v1 : 0.f; \
        zsm[(16 + lg * 4 + _j) * 264 + (G) * 64 + w * 16 + lr] = (_Float16)_v1; \
      } } } while (0)

    // phase for window pass K (<15): write chunk K+1, issue K+4, barrier, compute, prefetch next B
#define WPH(K, BU, BL, NPTR, NSTR) do { \
    WRITECH((K) + 1); \
    if ((K) <= 12) ISSUE((K) + 4); \
    PH_TOP(); \
    WCOMP(128 * (K), 0, 8, BU, true, true, b1 + (K) * 64, ((K) & 3) * 64); \
    LOADB8(BL, NPTR, NSTR); } while (0)

    // ---- prologue ----
    ISSUE(0); ISSUE(1); ISSUE(2);
    WRITECH(0);
    ISSUE(3);
    LOADB8(Ba, wsW1, 256);                       // B(k=0)

    // ---- group 0 ----
    WPH(0,  Ba, Bb, wsW1 + 1 * 16384, 256);
    WPH(1,  Bb, Ba, wsW1 + 2 * 16384, 256);
    WPH(2,  Ba, Bb, wsW1 + 3 * 16384, 256);
    WPH(3,  Bb, Ba, wsW2 + 0 * 16384, 256);
    PH_TOP(); L2COMP(Ba, 0); LOADB8(Bb, wsW1 + 4 * 16384, 256);
    // ---- group 1 ----
    WPH(4,  Bb, Ba, wsW1 + 5 * 16384, 256);
    WPH(5,  Ba, Bb, wsW1 + 6 * 16384, 256);
    WPH(6,  Bb, Ba, wsW1 + 7 * 16384, 256);
    WPH(7,  Ba, Bb, wsW2 + 1 * 16384, 256);
    PH_TOP(); L2COMP(Bb, 1); LOADB8(Ba, wsW1 + 8 * 16384, 256);
    // ---- group 2 ----
    WPH(8,  Ba, Bb, wsW1 + 9 * 16384, 256);
    WPH(9,  Bb, Ba, wsW1 + 10 * 16384, 256);
    WPH(10, Ba, Bb, wsW1 + 11 * 16384, 256);
    WPH(11, Bb, Ba, wsW2 + 2 * 16384, 256);
    PH_TOP(); L2COMP(Ba, 2); LOADB8(Bb, wsW1 + 12 * 16384, 256);
    // ---- group 3 (window 15 = y16 split into 15a/15b) ----
    WPH(12, Bb, Ba, wsW1 + 13 * 16384, 256);
    WPH(13, Ba, Bb, wsW1 + 14 * 16384, 256);
    WPH(14, Bb, Ba, wsW16, 384);                 // load B(15a) = W16 kk 0..7
    // 15a: use Ba, accumulate only; write chunk 16; load B(15b) = W16 kk 8..11
    WRITECH(16);
    PH_TOP();
    WCOMP(1816, 0, 8, Ba, true, false, b16, 192);
    LOADB4(Bb, wsW16, 384, 8);
    // 15b: use Bb[0..3], finish + store y16; load B(L2_3) = W2[3]
    PH_TOP();
    WCOMP(1816, 8, 4, Bb, false, true, b16, 192);
    LOADB8(Ba, wsW2 + 3 * 16384, 256);
    // L2_3
    PH_TOP(); L2COMP(Ba, 3);

    // ---- layer 3 ----
    PH_TOP();
    {
        f16x8 az0[8], az1[8];
        #pragma unroll
        for (int kk = 0; kk < 8; ++kk) {
            const _Float16* pz = zsm + lr * 264 + kk * 32 + lg * 8;
            az0[kk] = *(const f16x8*)pz;
            az1[kk] = *(const f16x8*)(pz + 16 * 264);
        }
        #pragma unroll 1
        for (int t = w; t < 17; t += 4) {
            f32x4 c0 = {0.f,0.f,0.f,0.f}, c1 = {0.f,0.f,0.f,0.f};
            #pragma unroll
            for (int kk = 0; kk < 8; ++kk) {
                f16x8 B = *(const f16x8*)(wsW3 + (size_t)(t * 16 + lr) * 256 + kk * 32 + lg * 8);
                c0 = MFMA16(az0[kk], B, c0);
                c1 = MFMA16(az1[kk], B, c1);
            }
            int o = t * 16 + lr;
            float bv = (o < 260) ? b3[o] : 0.f;
            #pragma unroll
            for (int j2 = 0; j2 < 4; ++j2) {
                float v0 = c0[j2] + bv; v0 = v0 > 0.f ? v0 : 0.f;
                hsm[(lg * 4 + j2) * 280 + o] = v0;
                float v1 = c1[j2] + bv; v1 = v1 > 0.f ? v1 : 0.f;
                hsm[(16 + lg * 4 + j2) * 280 + o] = v1;
            }
        }
    }
    PH_TOP();

    // ---- pooling (10 x 26) + softmax; threads 0..31 each own one row ----
    if (tid < 32) {
        int row = tid;
        float p[10];
        #pragma unroll
        for (int c = 0; c < 10; ++c) {
            float s = 0.f;
            #pragma unroll
            for (int u = 0; u < 26; ++u) s += hsm[row * 280 + c * 26 + u];
            p[c] = s;
        }
        float m = p[0];
        #pragma unroll
        for (int c = 1; c < 10; ++c) m = fmaxf(m, p[c]);
        float e[10], se = 0.f;
        #pragma unroll
        for (int c = 0; c < 10; ++c) { e[c] = expf(p[c] - m); se += e[c]; }
        float inv = 1.f / se;
        float* orow = out + (size_t)(bid * 32 + row) * 10;
        #pragma unroll
        for (int c = 0; c < 10; ++c) orow[c] = e[c] * inv;
    }

#undef PH_TOP
#undef ISSUE
#undef WRITECH
#undef LOADB8
#undef LOADB4
#undef WCOMP
#undef L2COMP
#undef WPH
}

extern "C" void kernel_launch(void* const* d_in, const int* in_sizes, int n_in,
                              void* d_out, int out_size, void* d_ws, size_t ws_size,
                              hipStream_t stream)
{
    const float* x   = (const float*)d_in[0];
    const float* W1  = (const float*)d_in[1];
    const float* b1  = (const float*)d_in[2];
    const float* W16 = (const float*)d_in[3];
    const float* b16 = (const float*)d_in[4];
    const float* W2  = (const float*)d_in[5];
    const float* b2  = (const float*)d_in[6];
    const float* W3  = (const float*)d_in[7];
    const float* b3  = (const float*)d_in[8];
    float*    out = (float*)d_out;
    _Float16* ws  = (_Float16*)d_ws;

    tea_prep<<<1584, 256, 0, stream>>>(W1, W16, W2, W3, ws);
    tea_main<<<512, 256, 0, stream>>>(x, b1, b16, b2, b3, ws, out);
}